// Round 4
// baseline (499.430 us; speedup 1.0000x reference)
//
#include <hip/hip_runtime.h>

// CNOT permutation on a batch of 2^n-amplitude state vectors (float32).
// out[b, j] = in[b, j ^ (1<<t2)]  if ((j >> c2) & 1)  else  in[b, j]
// with c2 = n - control - 1, t2 = n - target - 1.
//
// R3 -> R4: R3's unroll-4 never produced ILP (VGPR stayed 20 -> compiler
// re-serialized into load/store pairs). Occupancy ~13 waves/CU x 1KB
// outstanding ~= 6-7KB/CU in-flight reads < ~9.2KB needed to cover 375ns
// HBM latency at 24.6 GB/s/CU -> latency-bound at 75% of copy ceiling.
// Fix: unroll 8 and FORCE 8-load-then-8-store clustering with
// sched_group_barrier (VMEM_READ=0x20, VMEM_WRITE=0x40) so hipcc cannot
// interleave them. Plain loads/stores (nt was neutral in R3).

typedef float v4f __attribute__((ext_vector_type(4)));

#define UNROLL 8

__global__ __launch_bounds__(256) void
cnot_kernel(const v4f* __restrict__ in, v4f* __restrict__ out,
            const int* __restrict__ ctrl_p, const int* __restrict__ tgt_p,
            const int* __restrict__ nq_p, unsigned int n_vec) {
  const int n  = nq_p[0];
  const int c2 = n - ctrl_p[0] - 1;
  const int t2 = n - tgt_p[0] - 1;

  const unsigned int tid    = blockIdx.x * blockDim.x + threadIdx.x;
  const unsigned int stride = gridDim.x * blockDim.x;

  if (c2 >= 2 && t2 >= 2) {
    // Vectorized path (benched config: c2=20, t2=13).
    const unsigned int cmask = 1u << (c2 - 2);  // control bit, float4 units
    const unsigned int tmask = 1u << (t2 - 2);  // target flip, float4 units

    unsigned int i = tid;
    const unsigned int strideU = stride * UNROLL;

    for (; i + (UNROLL - 1u) * stride < n_vec; i += strideU) {
      unsigned int idx[UNROLL];
      unsigned int src[UNROLL];
      v4f v[UNROLL];
#pragma unroll
      for (int u = 0; u < UNROLL; ++u) {
        idx[u] = i + (unsigned int)u * stride;
        src[u] = (idx[u] & cmask) ? (idx[u] ^ tmask) : idx[u];
      }
#pragma unroll
      for (int u = 0; u < UNROLL; ++u) {
        v[u] = in[src[u]];
      }
      // Force the 8 reads to issue as one cluster before any store.
      __builtin_amdgcn_sched_group_barrier(0x20 /*VMEM_READ*/, UNROLL, 0);
#pragma unroll
      for (int u = 0; u < UNROLL; ++u) {
        out[idx[u]] = v[u];
      }
      __builtin_amdgcn_sched_group_barrier(0x40 /*VMEM_WRITE*/, UNROLL, 0);
    }
    // Tail (not taken for the benched shape: n_vec % (8*stride) == 0).
    for (; i < n_vec; i += stride) {
      const unsigned int s = (i & cmask) ? (i ^ tmask) : i;
      out[i] = in[s];
    }
  } else {
    // Scalar fallback (correctness only; not expected to run here).
    const float* inf  = (const float*)in;
    float*       outf = (float*)out;
    const unsigned int cm = 1u << c2;
    const unsigned int tm = 1u << t2;
    const unsigned int n_el = n_vec * 4u;
    for (unsigned int e = tid; e < n_el; e += stride) {
      const unsigned int s = (e & cm) ? (e ^ tm) : e;
      outf[e] = inf[s];
    }
  }
}

extern "C" void kernel_launch(void* const* d_in, const int* in_sizes, int n_in,
                              void* d_out, int out_size, void* d_ws, size_t ws_size,
                              hipStream_t stream) {
  const float* state = (const float*)d_in[0];
  const int* control = (const int*)d_in[1];
  const int* target  = (const int*)d_in[2];
  const int* nq      = (const int*)d_in[3];
  float* out = (float*)d_out;

  const unsigned int n_el  = (unsigned int)in_sizes[0];  // 16 * 2^24 = 2^28
  const unsigned int n_vec = n_el / 4u;                  // 2^26 float4s

  dim3 block(256);
  dim3 grid(2048);  // 8 blocks/CU resident; 16 float4s/thread/loop-pass
  hipLaunchKernelGGL(cnot_kernel, grid, block, 0, stream,
                     (const v4f*)state, (v4f*)out,
                     control, target, nq, n_vec);
}

// Round 5
// 353.623 us; speedup vs baseline: 1.4123x; 1.4123x over previous
//
#include <hip/hip_runtime.h>

// CNOT permutation on a batch of 2^n-amplitude state vectors (float32).
// out[b, j] = in[b, j ^ (1<<t2)]  if ((j >> c2) & 1)  else  in[b, j]
// with c2 = n - control - 1, t2 = n - target - 1.
//
// R4 -> R5: per-wave ILP attempts regressed (R3 neutral, R4 -10%). R3's
// profile showed OccupancyPercent ~40% (13 waves/CU): the 2048-block grid
// exactly fills the 8192 wave slots only under perfect dispatch. Latency
// math: ~9.2 KB in-flight reads/CU needed; 13 waves x 1KB x ~0.5 = 6.5 KB
// -> predicts the observed 4.75 TB/s. Fix = max TLP: ONE float4 per thread,
// no loop, 262144 blocks; CP backfills retiring blocks so residency stays
// at the 32-wave/CU cap with one outstanding 1KB load per wave.

typedef float v4f __attribute__((ext_vector_type(4)));

__global__ __launch_bounds__(256) void
cnot_kernel(const v4f* __restrict__ in, v4f* __restrict__ out,
            const int* __restrict__ ctrl_p, const int* __restrict__ tgt_p,
            const int* __restrict__ nq_p, unsigned int n_vec) {
  const int n  = nq_p[0];
  const int c2 = n - ctrl_p[0] - 1;
  const int t2 = n - tgt_p[0] - 1;

  const unsigned int i = blockIdx.x * blockDim.x + threadIdx.x;
  if (i >= n_vec) return;

  if (c2 >= 2 && t2 >= 2) {
    // Vectorized path (benched config: c2=20, t2=13).
    const unsigned int cmask = 1u << (c2 - 2);  // control bit, float4 units
    const unsigned int tmask = 1u << (t2 - 2);  // target flip, float4 units
    const unsigned int src = (i & cmask) ? (i ^ tmask) : i;
    out[i] = in[src];
  } else {
    // Scalar fallback (correctness only; not expected to run here).
    const float* inf  = (const float*)in;
    float*       outf = (float*)out;
    const unsigned int cm = 1u << c2;
    const unsigned int tm = 1u << t2;
#pragma unroll
    for (int k = 0; k < 4; ++k) {
      const unsigned int e = i * 4u + (unsigned int)k;
      const unsigned int s = (e & cm) ? (e ^ tm) : e;
      outf[e] = inf[s];
    }
  }
}

extern "C" void kernel_launch(void* const* d_in, const int* in_sizes, int n_in,
                              void* d_out, int out_size, void* d_ws, size_t ws_size,
                              hipStream_t stream) {
  const float* state = (const float*)d_in[0];
  const int* control = (const int*)d_in[1];
  const int* target  = (const int*)d_in[2];
  const int* nq      = (const int*)d_in[3];
  float* out = (float*)d_out;

  const unsigned int n_el  = (unsigned int)in_sizes[0];  // 16 * 2^24 = 2^28
  const unsigned int n_vec = n_el / 4u;                  // 2^26 float4s

  dim3 block(256);
  dim3 grid((n_vec + 255u) / 256u);  // 262144 blocks: one float4 per thread
  hipLaunchKernelGGL(cnot_kernel, grid, block, 0, stream,
                     (const v4f*)state, (v4f*)out,
                     control, target, nq, n_vec);
}